// Round 1
// baseline (1041.377 us; speedup 1.0000x reference)
//
#include <hip/hip_runtime.h>
#include <hip/hip_bf16.h>

#define LEAKY 0.2f

// ---------------- CSR build ----------------

__global__ __launch_bounds__(256) void count_kernel(const int* __restrict__ ei,
                                                    int* __restrict__ cnt,
                                                    int E, int ET) {
    int e = blockIdx.x * 256 + threadIdx.x;
    if (e >= ET) return;
    int d = (e < E) ? ei[E + e] : (e - E);
    atomicAdd(&cnt[d], 1);
}

__global__ __launch_bounds__(1024) void scan_kernel(const int* __restrict__ cnt,
                                                    int* __restrict__ rowptr, int N) {
    __shared__ int sums[1024];
    int tid = threadIdx.x;
    int chunk = (N + 1023) >> 10;
    int begin = tid * chunk;
    int end = min(begin + chunk, N);
    int s = 0;
    for (int i = begin; i < end; i++) s += cnt[i];
    sums[tid] = s;
    __syncthreads();
    for (int off = 1; off < 1024; off <<= 1) {
        int v = 0;
        if (tid >= off) v = sums[tid - off];
        __syncthreads();
        sums[tid] += v;
        __syncthreads();
    }
    int base = (tid == 0) ? 0 : sums[tid - 1];
    for (int i = begin; i < end; i++) { rowptr[i] = base; base += cnt[i]; }
    if (tid == 0) rowptr[N] = sums[1023];
}

__global__ __launch_bounds__(256) void scatter_kernel(const int* __restrict__ ei,
                                                      const int* __restrict__ rowptr,
                                                      int* __restrict__ cursor,
                                                      int* __restrict__ perm,
                                                      int E, int ET) {
    int e = blockIdx.x * 256 + threadIdx.x;
    if (e >= ET) return;
    int s, d;
    if (e < E) { s = ei[e]; d = ei[E + e]; } else { s = e - E; d = s; }
    int pos = atomicAdd(&cursor[d], 1);
    perm[rowptr[d] + pos] = s;  // store src node id directly
}

// ---------------- GEMM: Hout[N,HC] = X[N,128] @ W[128,HC] ----------------

template <int NC>  // HC = NC*32
__global__ __launch_bounds__(256) void gemm_kernel(const float* __restrict__ X,
                                                   const float* __restrict__ W,
                                                   float* __restrict__ Hout, int N) {
    constexpr int K = 128;
    constexpr int HC = NC * 32;
    __shared__ float Xs[8][K];
    int tx = threadIdx.x, ty = threadIdx.y;
    int tid = ty * 32 + tx;
    int row0 = blockIdx.x * 8;
    for (int i = tid; i < 8 * K; i += 256) {
        int r = i >> 7, k = i & 127;
        int gr = row0 + r;
        Xs[r][k] = (gr < N) ? X[(size_t)gr * K + k] : 0.f;
    }
    __syncthreads();
    int row = row0 + ty;
    if (row >= N) return;
    float acc[NC];
#pragma unroll
    for (int j = 0; j < NC; j++) acc[j] = 0.f;
    const float* wp = W + tx;
    for (int k = 0; k < K; k++) {
        float xk = Xs[ty][k];
        const float* wr = wp + (size_t)k * HC;
#pragma unroll
        for (int j = 0; j < NC; j++) acc[j] = fmaf(xk, wr[j * 32], acc[j]);
    }
    float* op = Hout + (size_t)row * HC + tx;
#pragma unroll
    for (int j = 0; j < NC; j++) op[j * 32] = acc[j];
}

// ---------------- per-node attention scores ----------------

template <int C>
__global__ __launch_bounds__(256) void attn_score_kernel(const float* __restrict__ Hf,
                                                         const float* __restrict__ as_,
                                                         const float* __restrict__ ad_,
                                                         float* __restrict__ es,
                                                         float* __restrict__ ed, int N) {
    int i = blockIdx.x * 256 + threadIdx.x;
    if (i >= N * 8) return;
    int n = i >> 3, h = i & 7;
    const float* hp = Hf + (size_t)n * 8 * C + h * C;
    const float* ap = as_ + h * C;
    const float* bp = ad_ + h * C;
    float s = 0.f, d = 0.f;
#pragma unroll 8
    for (int c = 0; c < C; c++) {
        float v = hp[c];
        s = fmaf(v, ap[c], s);
        d = fmaf(v, bp[c], d);
    }
    es[i] = s;
    ed[i] = d;
}

// ---------------- wave-per-dst softmax + aggregation ----------------
// lane layout for phases 1/2: head = lane&7, edge-slot = lane>>3 (8 edges/iter)
// phase 3: lane owns feature elements idx = lane + p*64 (HC is a multiple of 64)

template <int C, bool FINAL>
__global__ __launch_bounds__(256) void agg_kernel(const float* __restrict__ Hf,
                                                  const float* __restrict__ es,
                                                  const float* __restrict__ ed,
                                                  const int* __restrict__ rowptr,
                                                  const int* __restrict__ perm,
                                                  const float* __restrict__ bias,
                                                  float* __restrict__ Out, int N) {
    constexpr int HC = 8 * C;
    constexpr int NP = HC / 64;
    __shared__ float sfeat[FINAL ? 4 : 1][FINAL ? HC : 1];
    int lane = threadIdx.x & 63;
    int wid = threadIdx.x >> 6;
    int d = blockIdx.x * 4 + wid;
    bool active = d < N;
    int start = 0, end = 0;
    if (active) { start = rowptr[d]; end = rowptr[d + 1]; }
    int h8 = lane & 7;
    float edh = active ? ed[d * 8 + h8] : 0.f;

    // phase 1: per-head max over edges
    float mx = -3.0e38f;
    for (int q = start + (lane >> 3); q < end; q += 8) {
        int s = perm[q];
        float v = es[s * 8 + h8] + edh;
        v = (v >= 0.f) ? v : LEAKY * v;
        mx = fmaxf(mx, v);
    }
#pragma unroll
    for (int m = 8; m < 64; m <<= 1) mx = fmaxf(mx, __shfl_xor(mx, m));

    // phase 2: per-head sum of exp
    float sum = 0.f;
    for (int q = start + (lane >> 3); q < end; q += 8) {
        int s = perm[q];
        float v = es[s * 8 + h8] + edh;
        v = (v >= 0.f) ? v : LEAKY * v;
        sum += __expf(v - mx);
    }
#pragma unroll
    for (int m = 8; m < 64; m <<= 1) sum += __shfl_xor(sum, m);
    float rden = 1.0f / (sum + 1e-16f);

    // phase 3: accumulate alpha * h[src]
    float acc[NP], mh[NP], rdh[NP], edp[NP];
    int hh[NP];
#pragma unroll
    for (int p = 0; p < NP; p++) {
        int idx = lane + p * 64;
        int h = idx / C;
        hh[p] = h;
        mh[p] = __shfl(mx, h);
        rdh[p] = __shfl(rden, h);
        edp[p] = __shfl(edh, h);
        acc[p] = 0.f;
    }
    for (int q = start; q < end; q++) {
        int s = perm[q];
        const float* hp = Hf + (size_t)s * HC;
#pragma unroll
        for (int p = 0; p < NP; p++) {
            float v = es[s * 8 + hh[p]] + edp[p];
            v = (v >= 0.f) ? v : LEAKY * v;
            float alpha = __expf(v - mh[p]) * rdh[p];
            acc[p] = fmaf(alpha, hp[lane + p * 64], acc[p]);
        }
    }

    if (!FINAL) {
        if (active) {
            float* op = Out + (size_t)d * HC;
#pragma unroll
            for (int p = 0; p < NP; p++) {
                int idx = lane + p * 64;
                float v = acc[p] + bias[idx];
                v = (v > 0.f) ? v : expm1f(v);  // ELU
                op[idx] = v;
            }
        }
    } else {
        // mean over heads + bias, via LDS stage
#pragma unroll
        for (int p = 0; p < NP; p++) sfeat[wid][lane + p * 64] = acc[p];
        __syncthreads();
        if (active && lane < C) {
            float s = 0.f;
#pragma unroll
            for (int h = 0; h < 8; h++) s += sfeat[wid][h * C + lane];
            Out[(size_t)d * C + lane] = s * 0.125f + bias[lane];
        }
    }
}

// ---------------- launch ----------------

extern "C" void kernel_launch(void* const* d_in, const int* in_sizes, int n_in,
                              void* d_out, int out_size, void* d_ws, size_t ws_size,
                              hipStream_t stream) {
    const float* x   = (const float*)d_in[0];
    const int*   ei  = (const int*)d_in[1];
    const float* W1  = (const float*)d_in[2];
    const float* a1s = (const float*)d_in[3];
    const float* a1d = (const float*)d_in[4];
    const float* b1  = (const float*)d_in[5];
    const float* W2  = (const float*)d_in[6];
    const float* a2s = (const float*)d_in[7];
    const float* a2d = (const float*)d_in[8];
    const float* b2  = (const float*)d_in[9];
    const float* W3  = (const float*)d_in[10];
    const float* a3s = (const float*)d_in[11];
    const float* a3d = (const float*)d_in[12];
    const float* b3  = (const float*)d_in[13];
    float* out = (float*)d_out;

    const int N = in_sizes[0] / 128;
    const int E = in_sizes[1] / 2;
    const int ET = E + N;

    char* p = (char*)d_ws;
    float* hbuf  = (float*)p; p += (size_t)N * 320 * 4;
    float* xbuf  = (float*)p; p += (size_t)N * 128 * 4;
    float* es    = (float*)p; p += (size_t)N * 8 * 4;
    float* edd   = (float*)p; p += (size_t)N * 8 * 4;
    int* cnt     = (int*)p;   p += (size_t)N * 4;
    int* rowptr  = (int*)p;   p += (size_t)(N + 1) * 4;
    int* perm    = (int*)p;   p += (size_t)ET * 4;

    // CSR build (shared by all 3 layers)
    hipMemsetAsync(cnt, 0, (size_t)N * 4, stream);
    count_kernel<<<(ET + 255) / 256, 256, 0, stream>>>(ei, cnt, E, ET);
    scan_kernel<<<1, 1024, 0, stream>>>(cnt, rowptr, N);
    hipMemsetAsync(cnt, 0, (size_t)N * 4, stream);
    scatter_kernel<<<(ET + 255) / 256, 256, 0, stream>>>(ei, rowptr, cnt, perm, E, ET);

    dim3 gb(32, 8);
    int gemm_grid = (N + 7) / 8;
    int nh_grid = (N * 8 + 255) / 256;
    int agg_grid = (N + 3) / 4;

    // layer 1: GAT(128 -> 8x16, concat) + ELU
    gemm_kernel<4><<<gemm_grid, gb, 0, stream>>>(x, W1, hbuf, N);
    attn_score_kernel<16><<<nh_grid, 256, 0, stream>>>(hbuf, a1s, a1d, es, edd, N);
    agg_kernel<16, false><<<agg_grid, 256, 0, stream>>>(hbuf, es, edd, rowptr, perm, b1, xbuf, N);

    // layer 2: GAT(128 -> 8x16, concat) + ELU
    gemm_kernel<4><<<gemm_grid, gb, 0, stream>>>(xbuf, W2, hbuf, N);
    attn_score_kernel<16><<<nh_grid, 256, 0, stream>>>(hbuf, a2s, a2d, es, edd, N);
    agg_kernel<16, false><<<agg_grid, 256, 0, stream>>>(hbuf, es, edd, rowptr, perm, b2, xbuf, N);

    // layer 3: GAT(128 -> 8x40, mean over heads)
    gemm_kernel<10><<<gemm_grid, gb, 0, stream>>>(xbuf, W3, hbuf, N);
    attn_score_kernel<40><<<nh_grid, 256, 0, stream>>>(hbuf, a3s, a3d, es, edd, N);
    agg_kernel<40, true><<<agg_grid, 256, 0, stream>>>(hbuf, es, edd, rowptr, perm, b3, out, N);
}

// Round 2
// 736.281 us; speedup vs baseline: 1.4144x; 1.4144x over previous
//
#include <hip/hip_runtime.h>
#include <hip/hip_bf16.h>

#define LEAKY 0.2f

// ---------------- CSR build ----------------

__global__ __launch_bounds__(256) void count_kernel(const int* __restrict__ ei,
                                                    int* __restrict__ cnt,
                                                    int E, int ET) {
    int e = blockIdx.x * 256 + threadIdx.x;
    if (e >= ET) return;
    int d = (e < E) ? ei[E + e] : (e - E);
    atomicAdd(&cnt[d], 1);
}

__global__ __launch_bounds__(1024) void scan_kernel(const int* __restrict__ cnt,
                                                    int* __restrict__ rowptr, int N) {
    __shared__ int sums[1024];
    int tid = threadIdx.x;
    int chunk = (N + 1023) >> 10;
    int begin = tid * chunk;
    int end = min(begin + chunk, N);
    int s = 0;
    for (int i = begin; i < end; i++) s += cnt[i];
    sums[tid] = s;
    __syncthreads();
    for (int off = 1; off < 1024; off <<= 1) {
        int v = 0;
        if (tid >= off) v = sums[tid - off];
        __syncthreads();
        sums[tid] += v;
        __syncthreads();
    }
    int base = (tid == 0) ? 0 : sums[tid - 1];
    for (int i = begin; i < end; i++) { rowptr[i] = base; base += cnt[i]; }
    if (tid == 0) rowptr[N] = sums[1023];
}

__global__ __launch_bounds__(256) void scatter_kernel(const int* __restrict__ ei,
                                                      const int* __restrict__ rowptr,
                                                      int* __restrict__ cursor,
                                                      int* __restrict__ perm,
                                                      int E, int ET) {
    int e = blockIdx.x * 256 + threadIdx.x;
    if (e >= ET) return;
    int s, d;
    if (e < E) { s = ei[e]; d = ei[E + e]; } else { s = e - E; d = s; }
    int pos = atomicAdd(&cursor[d], 1);
    perm[rowptr[d] + pos] = s;  // store src node id directly
}

// ---------------- GEMM: Hout[M,HC] = X[M,128] @ W[128,HC] ----------------
// Register-tiled: block tile 128x64, BK=32, 256 threads, 8x4 micro-tile.
// Xs stored transposed [k][m] (stride 132 to kill write conflicts, keeps
// 16B alignment for ds_read_b128); Ws stored [k][n] directly.

#define XS_LD 132

__global__ __launch_bounds__(256) void gemm_kernel(const float* __restrict__ X,
                                                   const float* __restrict__ W,
                                                   float* __restrict__ Hout,
                                                   int M, int HC) {
    constexpr int K = 128;
    __shared__ float Xs[32 * XS_LD];
    __shared__ float Ws[32 * 64];

    int tid = threadIdx.x;
    int tx = tid & 15;        // col group: owns cols 4*tx..+3
    int ty = tid >> 4;        // row group: owns rows 8*ty..+7
    int m0 = blockIdx.x * 128;
    int n0 = blockIdx.y * 64;

    float acc[8][4];
#pragma unroll
    for (int r = 0; r < 8; r++)
#pragma unroll
        for (int c = 0; c < 4; c++) acc[r][c] = 0.f;

    // load indices
    int lx_m = tid >> 3;          // 0..31
    int lx_kq = tid & 7;          // float4 index along k
    int lw_k = tid >> 4;          // 0..15
    int lw_nq = tid & 15;         // float4 index along n

    for (int k0 = 0; k0 < K; k0 += 32) {
        // --- stage X tile (transposed) ---
#pragma unroll
        for (int p = 0; p < 4; p++) {
            int mi = p * 32 + lx_m;
            int row = m0 + mi;
            float4 v = make_float4(0.f, 0.f, 0.f, 0.f);
            if (row < M)
                v = *(const float4*)&X[(size_t)row * K + k0 + 4 * lx_kq];
            Xs[(4 * lx_kq + 0) * XS_LD + mi] = v.x;
            Xs[(4 * lx_kq + 1) * XS_LD + mi] = v.y;
            Xs[(4 * lx_kq + 2) * XS_LD + mi] = v.z;
            Xs[(4 * lx_kq + 3) * XS_LD + mi] = v.w;
        }
        // --- stage W tile ---
#pragma unroll
        for (int p = 0; p < 2; p++) {
            int kr = p * 16 + lw_k;
            float4 v = *(const float4*)&W[(size_t)(k0 + kr) * HC + n0 + 4 * lw_nq];
            *(float4*)&Ws[kr * 64 + 4 * lw_nq] = v;
        }
        __syncthreads();

#pragma unroll 8
        for (int kk = 0; kk < 32; kk++) {
            float4 a0 = *(float4*)&Xs[kk * XS_LD + ty * 8];
            float4 a1 = *(float4*)&Xs[kk * XS_LD + ty * 8 + 4];
            float4 bv = *(float4*)&Ws[kk * 64 + tx * 4];
            float av[8] = {a0.x, a0.y, a0.z, a0.w, a1.x, a1.y, a1.z, a1.w};
            float bw[4] = {bv.x, bv.y, bv.z, bv.w};
#pragma unroll
            for (int r = 0; r < 8; r++)
#pragma unroll
                for (int c = 0; c < 4; c++)
                    acc[r][c] = fmaf(av[r], bw[c], acc[r][c]);
        }
        __syncthreads();
    }

#pragma unroll
    for (int r = 0; r < 8; r++) {
        int row = m0 + ty * 8 + r;
        if (row < M) {
            float4 v = make_float4(acc[r][0], acc[r][1], acc[r][2], acc[r][3]);
            *(float4*)&Hout[(size_t)row * HC + n0 + tx * 4] = v;
        }
    }
}

// ---------------- per-node attention scores ----------------

template <int C>
__global__ __launch_bounds__(256) void attn_score_kernel(const float* __restrict__ Hf,
                                                         const float* __restrict__ as_,
                                                         const float* __restrict__ ad_,
                                                         float* __restrict__ es,
                                                         float* __restrict__ ed, int N) {
    int i = blockIdx.x * 256 + threadIdx.x;
    if (i >= N * 8) return;
    int n = i >> 3, h = i & 7;
    const float* hp = Hf + (size_t)n * 8 * C + h * C;
    const float* ap = as_ + h * C;
    const float* bp = ad_ + h * C;
    float s = 0.f, d = 0.f;
#pragma unroll 8
    for (int c = 0; c < C; c++) {
        float v = hp[c];
        s = fmaf(v, ap[c], s);
        d = fmaf(v, bp[c], d);
    }
    es[i] = s;
    ed[i] = d;
}

// ---------------- wave-per-dst softmax + aggregation ----------------
// lane layout for phases 1/2: head = lane&7, edge-slot = lane>>3 (8 edges/iter)
// phase 3: lane owns feature elements idx = lane + p*64 (HC is a multiple of 64)

template <int C, bool FINAL>
__global__ __launch_bounds__(256) void agg_kernel(const float* __restrict__ Hf,
                                                  const float* __restrict__ es,
                                                  const float* __restrict__ ed,
                                                  const int* __restrict__ rowptr,
                                                  const int* __restrict__ perm,
                                                  const float* __restrict__ bias,
                                                  float* __restrict__ Out, int N) {
    constexpr int HC = 8 * C;
    constexpr int NP = HC / 64;
    __shared__ float sfeat[FINAL ? 4 : 1][FINAL ? HC : 1];
    int lane = threadIdx.x & 63;
    int wid = threadIdx.x >> 6;
    int d = blockIdx.x * 4 + wid;
    bool active = d < N;
    int start = 0, end = 0;
    if (active) { start = rowptr[d]; end = rowptr[d + 1]; }
    int h8 = lane & 7;
    float edh = active ? ed[d * 8 + h8] : 0.f;

    // phase 1: per-head max over edges
    float mx = -3.0e38f;
    for (int q = start + (lane >> 3); q < end; q += 8) {
        int s = perm[q];
        float v = es[s * 8 + h8] + edh;
        v = (v >= 0.f) ? v : LEAKY * v;
        mx = fmaxf(mx, v);
    }
#pragma unroll
    for (int m = 8; m < 64; m <<= 1) mx = fmaxf(mx, __shfl_xor(mx, m));

    // phase 2: per-head sum of exp
    float sum = 0.f;
    for (int q = start + (lane >> 3); q < end; q += 8) {
        int s = perm[q];
        float v = es[s * 8 + h8] + edh;
        v = (v >= 0.f) ? v : LEAKY * v;
        sum += __expf(v - mx);
    }
#pragma unroll
    for (int m = 8; m < 64; m <<= 1) sum += __shfl_xor(sum, m);
    float rden = 1.0f / (sum + 1e-16f);

    // phase 3: accumulate alpha * h[src]
    float acc[NP], mh[NP], rdh[NP], edp[NP];
    int hh[NP];
#pragma unroll
    for (int p = 0; p < NP; p++) {
        int idx = lane + p * 64;
        int h = idx / C;
        hh[p] = h;
        mh[p] = __shfl(mx, h);
        rdh[p] = __shfl(rden, h);
        edp[p] = __shfl(edh, h);
        acc[p] = 0.f;
    }
    for (int q = start; q < end; q++) {
        int s = perm[q];
        const float* hp = Hf + (size_t)s * HC;
#pragma unroll
        for (int p = 0; p < NP; p++) {
            float v = es[s * 8 + hh[p]] + edp[p];
            v = (v >= 0.f) ? v : LEAKY * v;
            float alpha = __expf(v - mh[p]) * rdh[p];
            acc[p] = fmaf(alpha, hp[lane + p * 64], acc[p]);
        }
    }

    if (!FINAL) {
        if (active) {
            float* op = Out + (size_t)d * HC;
#pragma unroll
            for (int p = 0; p < NP; p++) {
                int idx = lane + p * 64;
                float v = acc[p] + bias[idx];
                v = (v > 0.f) ? v : expm1f(v);  // ELU
                op[idx] = v;
            }
        }
    } else {
        // mean over heads + bias, via LDS stage
#pragma unroll
        for (int p = 0; p < NP; p++) sfeat[wid][lane + p * 64] = acc[p];
        __syncthreads();
        if (active && lane < C) {
            float s = 0.f;
#pragma unroll
            for (int h = 0; h < 8; h++) s += sfeat[wid][h * C + lane];
            Out[(size_t)d * C + lane] = s * 0.125f + bias[lane];
        }
    }
}

// ---------------- launch ----------------

extern "C" void kernel_launch(void* const* d_in, const int* in_sizes, int n_in,
                              void* d_out, int out_size, void* d_ws, size_t ws_size,
                              hipStream_t stream) {
    const float* x   = (const float*)d_in[0];
    const int*   ei  = (const int*)d_in[1];
    const float* W1  = (const float*)d_in[2];
    const float* a1s = (const float*)d_in[3];
    const float* a1d = (const float*)d_in[4];
    const float* b1  = (const float*)d_in[5];
    const float* W2  = (const float*)d_in[6];
    const float* a2s = (const float*)d_in[7];
    const float* a2d = (const float*)d_in[8];
    const float* b2  = (const float*)d_in[9];
    const float* W3  = (const float*)d_in[10];
    const float* a3s = (const float*)d_in[11];
    const float* a3d = (const float*)d_in[12];
    const float* b3  = (const float*)d_in[13];
    float* out = (float*)d_out;

    const int N = in_sizes[0] / 128;
    const int E = in_sizes[1] / 2;
    const int ET = E + N;

    char* p = (char*)d_ws;
    float* hbuf  = (float*)p; p += (size_t)N * 320 * 4;
    float* xbuf  = (float*)p; p += (size_t)N * 128 * 4;
    float* es    = (float*)p; p += (size_t)N * 8 * 4;
    float* edd   = (float*)p; p += (size_t)N * 8 * 4;
    int* cnt     = (int*)p;   p += (size_t)N * 4;
    int* rowptr  = (int*)p;   p += (size_t)(N + 1) * 4;
    int* perm    = (int*)p;   p += (size_t)ET * 4;

    // CSR build (shared by all 3 layers)
    hipMemsetAsync(cnt, 0, (size_t)N * 4, stream);
    count_kernel<<<(ET + 255) / 256, 256, 0, stream>>>(ei, cnt, E, ET);
    scan_kernel<<<1, 1024, 0, stream>>>(cnt, rowptr, N);
    hipMemsetAsync(cnt, 0, (size_t)N * 4, stream);
    scatter_kernel<<<(ET + 255) / 256, 256, 0, stream>>>(ei, rowptr, cnt, perm, E, ET);

    int nh_grid = (N * 8 + 255) / 256;
    int agg_grid = (N + 3) / 4;
    dim3 g128((N + 127) / 128, 2);   // HC=128
    dim3 g320((N + 127) / 128, 5);   // HC=320

    // layer 1: GAT(128 -> 8x16, concat) + ELU
    gemm_kernel<<<g128, 256, 0, stream>>>(x, W1, hbuf, N, 128);
    attn_score_kernel<16><<<nh_grid, 256, 0, stream>>>(hbuf, a1s, a1d, es, edd, N);
    agg_kernel<16, false><<<agg_grid, 256, 0, stream>>>(hbuf, es, edd, rowptr, perm, b1, xbuf, N);

    // layer 2: GAT(128 -> 8x16, concat) + ELU
    gemm_kernel<<<g128, 256, 0, stream>>>(xbuf, W2, hbuf, N, 128);
    attn_score_kernel<16><<<nh_grid, 256, 0, stream>>>(hbuf, a2s, a2d, es, edd, N);
    agg_kernel<16, false><<<agg_grid, 256, 0, stream>>>(hbuf, es, edd, rowptr, perm, b2, xbuf, N);

    // layer 3: GAT(128 -> 8x40, mean over heads)
    gemm_kernel<<<g320, 256, 0, stream>>>(xbuf, W3, hbuf, N, 320);
    attn_score_kernel<40><<<nh_grid, 256, 0, stream>>>(hbuf, a3s, a3d, es, edd, N);
    agg_kernel<40, true><<<agg_grid, 256, 0, stream>>>(hbuf, es, edd, rowptr, perm, b3, out, N);
}

// Round 3
// 649.488 us; speedup vs baseline: 1.6034x; 1.1336x over previous
//
#include <hip/hip_runtime.h>
#include <hip/hip_bf16.h>

#define LEAKY 0.2f

// ---------------- CSR build ----------------

__global__ __launch_bounds__(256) void count_kernel(const int* __restrict__ ei,
                                                    int* __restrict__ cnt,
                                                    int E, int ET) {
    int e = blockIdx.x * 256 + threadIdx.x;
    if (e >= ET) return;
    int d = (e < E) ? ei[E + e] : (e - E);
    atomicAdd(&cnt[d], 1);
}

__global__ __launch_bounds__(1024) void scan_kernel(const int* __restrict__ cnt,
                                                    int* __restrict__ rowptr, int N) {
    __shared__ int sums[1024];
    int tid = threadIdx.x;
    int chunk = (N + 1023) >> 10;
    int begin = tid * chunk;
    int end = min(begin + chunk, N);
    int s = 0;
    for (int i = begin; i < end; i++) s += cnt[i];
    sums[tid] = s;
    __syncthreads();
    for (int off = 1; off < 1024; off <<= 1) {
        int v = 0;
        if (tid >= off) v = sums[tid - off];
        __syncthreads();
        sums[tid] += v;
        __syncthreads();
    }
    int base = (tid == 0) ? 0 : sums[tid - 1];
    for (int i = begin; i < end; i++) { rowptr[i] = base; base += cnt[i]; }
    if (tid == 0) rowptr[N] = sums[1023];
}

__global__ __launch_bounds__(256) void scatter_kernel(const int* __restrict__ ei,
                                                      const int* __restrict__ rowptr,
                                                      int* __restrict__ cursor,
                                                      int* __restrict__ perm,
                                                      int E, int ET) {
    int e = blockIdx.x * 256 + threadIdx.x;
    if (e >= ET) return;
    int s, d;
    if (e < E) { s = ei[e]; d = ei[E + e]; } else { s = e - E; d = s; }
    int pos = atomicAdd(&cursor[d], 1);
    perm[rowptr[d] + pos] = s;  // store src node id directly
}

// ---------------- GEMM: Hout[M,HC] = X[M,128] @ W[128,HC] ----------------

#define XS_LD 132

__global__ __launch_bounds__(256) void gemm_kernel(const float* __restrict__ X,
                                                   const float* __restrict__ W,
                                                   float* __restrict__ Hout,
                                                   int M, int HC) {
    constexpr int K = 128;
    __shared__ float Xs[32 * XS_LD];
    __shared__ float Ws[32 * 64];

    int tid = threadIdx.x;
    int tx = tid & 15;
    int ty = tid >> 4;
    int m0 = blockIdx.x * 128;
    int n0 = blockIdx.y * 64;

    float acc[8][4];
#pragma unroll
    for (int r = 0; r < 8; r++)
#pragma unroll
        for (int c = 0; c < 4; c++) acc[r][c] = 0.f;

    int lx_m = tid >> 3;
    int lx_kq = tid & 7;
    int lw_k = tid >> 4;
    int lw_nq = tid & 15;

    for (int k0 = 0; k0 < K; k0 += 32) {
#pragma unroll
        for (int p = 0; p < 4; p++) {
            int mi = p * 32 + lx_m;
            int row = m0 + mi;
            float4 v = make_float4(0.f, 0.f, 0.f, 0.f);
            if (row < M)
                v = *(const float4*)&X[(size_t)row * K + k0 + 4 * lx_kq];
            Xs[(4 * lx_kq + 0) * XS_LD + mi] = v.x;
            Xs[(4 * lx_kq + 1) * XS_LD + mi] = v.y;
            Xs[(4 * lx_kq + 2) * XS_LD + mi] = v.z;
            Xs[(4 * lx_kq + 3) * XS_LD + mi] = v.w;
        }
#pragma unroll
        for (int p = 0; p < 2; p++) {
            int kr = p * 16 + lw_k;
            float4 v = *(const float4*)&W[(size_t)(k0 + kr) * HC + n0 + 4 * lw_nq];
            *(float4*)&Ws[kr * 64 + 4 * lw_nq] = v;
        }
        __syncthreads();

#pragma unroll 8
        for (int kk = 0; kk < 32; kk++) {
            float4 a0 = *(float4*)&Xs[kk * XS_LD + ty * 8];
            float4 a1 = *(float4*)&Xs[kk * XS_LD + ty * 8 + 4];
            float4 bv = *(float4*)&Ws[kk * 64 + tx * 4];
            float av[8] = {a0.x, a0.y, a0.z, a0.w, a1.x, a1.y, a1.z, a1.w};
            float bw[4] = {bv.x, bv.y, bv.z, bv.w};
#pragma unroll
            for (int r = 0; r < 8; r++)
#pragma unroll
                for (int c = 0; c < 4; c++)
                    acc[r][c] = fmaf(av[r], bw[c], acc[r][c]);
        }
        __syncthreads();
    }

#pragma unroll
    for (int r = 0; r < 8; r++) {
        int row = m0 + ty * 8 + r;
        if (row < M) {
            float4 v = make_float4(acc[r][0], acc[r][1], acc[r][2], acc[r][3]);
            *(float4*)&Hout[(size_t)row * HC + n0 + tx * 4] = v;
        }
    }
}

// ---------------- per-node attention scores ----------------

template <int C>
__global__ __launch_bounds__(256) void attn_score_kernel(const float* __restrict__ Hf,
                                                         const float* __restrict__ as_,
                                                         const float* __restrict__ ad_,
                                                         float* __restrict__ es,
                                                         float* __restrict__ ed, int N) {
    int i = blockIdx.x * 256 + threadIdx.x;
    if (i >= N * 8) return;
    int n = i >> 3, h = i & 7;
    const float* hp = Hf + (size_t)n * 8 * C + h * C;
    const float* ap = as_ + h * C;
    const float* bp = ad_ + h * C;
    float s = 0.f, d = 0.f;
#pragma unroll 8
    for (int c = 0; c < C; c++) {
        float v = hp[c];
        s = fmaf(v, ap[c], s);
        d = fmaf(v, bp[c], d);
    }
    es[i] = s;
    ed[i] = d;
}

// ---------------- wave-per-dst softmax + aggregation ----------------
// Phase 1 (max) uses 8-edge x 8-head lane layout (head = lane&7, eslot = lane>>3).
// Fused phase 2+3: per 8-edge chunk, compute unnormalized alpha per (edge,head)
// once in the 8x8 layout; accumulate denom; then an unrolled per-edge loop
// broadcasts src (readlane -> SGPR, scalar addressing) and alpha (ds_bpermute)
// and gathers features vectorized. Normalize by denom at the end.
//
// Feature lane layout: C=16 (HC=128): float2 at 2*lane.
//                      C=40 (HC=320): float4 at 4*lane + float at 256+lane.

template <int C, bool FINAL>
__global__ __launch_bounds__(256) void agg_kernel(const float* __restrict__ Hf,
                                                  const float* __restrict__ es,
                                                  const float* __restrict__ ed,
                                                  const int* __restrict__ rowptr,
                                                  const int* __restrict__ perm,
                                                  const float* __restrict__ bias,
                                                  float* __restrict__ Out, int N) {
    constexpr int HC = 8 * C;
    constexpr int NP = HC / 64;  // floats per lane
    __shared__ float sfeat[FINAL ? 4 : 1][FINAL ? HC : 1];
    int lane = threadIdx.x & 63;
    int wid = threadIdx.x >> 6;
    int d = blockIdx.x * 4 + wid;
    bool active = d < N;
    int start = 0, end = 0;
    if (active) { start = rowptr[d]; end = rowptr[d + 1]; }
    start = __builtin_amdgcn_readfirstlane(start);
    end = __builtin_amdgcn_readfirstlane(end);
    int h8 = lane & 7;
    int eslot = lane >> 3;
    float edh = active ? ed[d * 8 + h8] : 0.f;

    // ---- phase 1: per-head max over edges ----
    float mx = -3.0e38f;
    for (int q = start + eslot; q < end; q += 8) {
        int s = perm[q];
        float v = es[s * 8 + h8] + edh;
        v = (v >= 0.f) ? v : LEAKY * v;
        mx = fmaxf(mx, v);
    }
#pragma unroll
    for (int m = 8; m < 64; m <<= 1) mx = fmaxf(mx, __shfl_xor(mx, m));
    // every lane now holds the max for its head h8

    // ---- feature-slice constants ----
    float acc[NP];
    int hh[NP];  // head owning each of this lane's feature elements
#pragma unroll
    for (int p = 0; p < NP; p++) acc[p] = 0.f;
    if constexpr (!FINAL) {
#pragma unroll
        for (int j = 0; j < 2; j++) hh[j] = (2 * lane + j) / C;
    } else {
#pragma unroll
        for (int j = 0; j < 4; j++) hh[j] = (4 * lane + j) / C;
        hh[4] = (256 + lane) / C;
    }

    // ---- fused phase 2+3 ----
    float dsum = 0.f;
    for (int q0 = start; q0 < end; q0 += 8) {
        int qq = q0 + eslot;
        int s_l = 0;
        float a_l = 0.f;
        if (qq < end) {
            s_l = perm[qq];
            float v = es[s_l * 8 + h8] + edh;
            v = (v >= 0.f) ? v : LEAKY * v;
            a_l = __expf(v - mx);
        }
        dsum += a_l;
#pragma unroll
        for (int e = 0; e < 8; e++) {
            if (q0 + e < end) {
                int s = __builtin_amdgcn_readlane(s_l, e * 8);
                const float* hp = Hf + (size_t)s * HC;
                if constexpr (!FINAL) {
                    float2 hv = *(const float2*)&hp[2 * lane];
                    float a0 = __shfl(a_l, e * 8 + hh[0]);
                    float a1 = __shfl(a_l, e * 8 + hh[1]);
                    acc[0] = fmaf(a0, hv.x, acc[0]);
                    acc[1] = fmaf(a1, hv.y, acc[1]);
                } else {
                    float4 hv = *(const float4*)&hp[4 * lane];
                    float h4 = hp[256 + lane];
                    float a0 = __shfl(a_l, e * 8 + hh[0]);
                    float a1 = __shfl(a_l, e * 8 + hh[1]);
                    float a2 = __shfl(a_l, e * 8 + hh[2]);
                    float a3 = __shfl(a_l, e * 8 + hh[3]);
                    float a4 = __shfl(a_l, e * 8 + hh[4]);
                    acc[0] = fmaf(a0, hv.x, acc[0]);
                    acc[1] = fmaf(a1, hv.y, acc[1]);
                    acc[2] = fmaf(a2, hv.z, acc[2]);
                    acc[3] = fmaf(a3, hv.w, acc[3]);
                    acc[4] = fmaf(a4, h4, acc[4]);
                }
            }
        }
    }

    // ---- normalize ----
#pragma unroll
    for (int m = 8; m < 64; m <<= 1) dsum += __shfl_xor(dsum, m);
    float rden = 1.0f / (dsum + 1e-16f);
#pragma unroll
    for (int p = 0; p < NP; p++) {
        float r = __shfl(rden, hh[p]);
        acc[p] *= r;
    }

    // ---- epilogue ----
    if constexpr (!FINAL) {
        if (active) {
            float* op = Out + (size_t)d * HC;
            float2 v;
            v.x = acc[0] + bias[2 * lane];
            v.y = acc[1] + bias[2 * lane + 1];
            v.x = (v.x > 0.f) ? v.x : expm1f(v.x);  // ELU
            v.y = (v.y > 0.f) ? v.y : expm1f(v.y);
            *(float2*)&op[2 * lane] = v;
        }
    } else {
#pragma unroll
        for (int j = 0; j < 4; j++) sfeat[wid][4 * lane + j] = acc[j];
        sfeat[wid][256 + lane] = acc[4];
        __syncthreads();
        if (active && lane < C) {
            float s = 0.f;
#pragma unroll
            for (int h = 0; h < 8; h++) s += sfeat[wid][h * C + lane];
            Out[(size_t)d * C + lane] = s * 0.125f + bias[lane];
        }
    }
}

// ---------------- launch ----------------

extern "C" void kernel_launch(void* const* d_in, const int* in_sizes, int n_in,
                              void* d_out, int out_size, void* d_ws, size_t ws_size,
                              hipStream_t stream) {
    const float* x   = (const float*)d_in[0];
    const int*   ei  = (const int*)d_in[1];
    const float* W1  = (const float*)d_in[2];
    const float* a1s = (const float*)d_in[3];
    const float* a1d = (const float*)d_in[4];
    const float* b1  = (const float*)d_in[5];
    const float* W2  = (const float*)d_in[6];
    const float* a2s = (const float*)d_in[7];
    const float* a2d = (const float*)d_in[8];
    const float* b2  = (const float*)d_in[9];
    const float* W3  = (const float*)d_in[10];
    const float* a3s = (const float*)d_in[11];
    const float* a3d = (const float*)d_in[12];
    const float* b3  = (const float*)d_in[13];
    float* out = (float*)d_out;

    const int N = in_sizes[0] / 128;
    const int E = in_sizes[1] / 2;
    const int ET = E + N;

    char* p = (char*)d_ws;
    float* hbuf  = (float*)p; p += (size_t)N * 320 * 4;
    float* xbuf  = (float*)p; p += (size_t)N * 128 * 4;
    float* es    = (float*)p; p += (size_t)N * 8 * 4;
    float* edd   = (float*)p; p += (size_t)N * 8 * 4;
    int* cnt     = (int*)p;   p += (size_t)N * 4;
    int* rowptr  = (int*)p;   p += (size_t)(N + 1) * 4;
    int* perm    = (int*)p;   p += (size_t)ET * 4;

    // CSR build (shared by all 3 layers)
    hipMemsetAsync(cnt, 0, (size_t)N * 4, stream);
    count_kernel<<<(ET + 255) / 256, 256, 0, stream>>>(ei, cnt, E, ET);
    scan_kernel<<<1, 1024, 0, stream>>>(cnt, rowptr, N);
    hipMemsetAsync(cnt, 0, (size_t)N * 4, stream);
    scatter_kernel<<<(ET + 255) / 256, 256, 0, stream>>>(ei, rowptr, cnt, perm, E, ET);

    int nh_grid = (N * 8 + 255) / 256;
    int agg_grid = (N + 3) / 4;
    dim3 g128((N + 127) / 128, 2);   // HC=128
    dim3 g320((N + 127) / 128, 5);   // HC=320

    // layer 1: GAT(128 -> 8x16, concat) + ELU
    gemm_kernel<<<g128, 256, 0, stream>>>(x, W1, hbuf, N, 128);
    attn_score_kernel<16><<<nh_grid, 256, 0, stream>>>(hbuf, a1s, a1d, es, edd, N);
    agg_kernel<16, false><<<agg_grid, 256, 0, stream>>>(hbuf, es, edd, rowptr, perm, b1, xbuf, N);

    // layer 2: GAT(128 -> 8x16, concat) + ELU
    gemm_kernel<<<g128, 256, 0, stream>>>(xbuf, W2, hbuf, N, 128);
    attn_score_kernel<16><<<nh_grid, 256, 0, stream>>>(hbuf, a2s, a2d, es, edd, N);
    agg_kernel<16, false><<<agg_grid, 256, 0, stream>>>(hbuf, es, edd, rowptr, perm, b2, xbuf, N);

    // layer 3: GAT(128 -> 8x40, mean over heads)
    gemm_kernel<<<g320, 256, 0, stream>>>(xbuf, W3, hbuf, N, 320);
    attn_score_kernel<40><<<nh_grid, 256, 0, stream>>>(hbuf, a3s, a3d, es, edd, N);
    agg_kernel<40, true><<<agg_grid, 256, 0, stream>>>(hbuf, es, edd, rowptr, perm, b3, out, N);
}